// Round 20
// baseline (973.097 us; speedup 1.0000x reference)
//
#include <hip/hip_runtime.h>
#include <hip/hip_bf16.h>
#include <cmath>

// ---------------------------------------------------------------------------
// TextEncoder: 4-layer post-LN transformer, B=2 N=2048 D=1024 H=16 dh=64 FF=4096
// R18: (1) attn P-pack -> bit-truncation (3 ops vs ~10 for RNE f2b; psum stays
// fp32-exact, 1/sum normalization tolerates the 2^-8 truncation). (2) weight
// transpose_cast rewritten: 64x32 tiles, coalesced float reads, 16B bf16x8
// stores (was scalar 2B). Rest unchanged from R17.
// ---------------------------------------------------------------------------

typedef __attribute__((ext_vector_type(8))) short bf16x8;
typedef __attribute__((ext_vector_type(4))) float f32x4;
typedef __hip_bfloat16 bf16;

#define DEV static __device__ __forceinline__

DEV unsigned short f2b(float f) {
    bf16 h = __float2bfloat16(f);
    return *reinterpret_cast<unsigned short*>(&h);
}

// truncation pack: two non-negative floats -> packed bf16 pair (lo | hi<<16)
DEV unsigned int pack_bf16_trunc(float lo, float hi) {
    unsigned int ulo = *reinterpret_cast<unsigned int*>(&lo);
    unsigned int uhi = *reinterpret_cast<unsigned int*>(&hi);
    return (uhi & 0xFFFF0000u) | (ulo >> 16);
}

DEV float b2f(unsigned short u) {
    unsigned int x = ((unsigned int)u) << 16;
    return *reinterpret_cast<float*>(&x);
}

// tanh-form gelu: max abs deviation from exact ~1e-3, ~10 VALU ops.
DEV float gelu_fast(float x) {
    float u = 0.7978845608028654f * fmaf(0.044715f * x, x * x, x);
    u = fminf(fmaxf(u, -15.f), 15.f);
    float t = __builtin_amdgcn_exp2f(u * 2.8853900817779268f);
    float th = (t - 1.0f) * __builtin_amdgcn_rcpf(t + 1.0f);
    return 0.5f * x * (1.0f + th);
}

DEV void gload_lds16(const bf16* g, bf16* l) {
    __builtin_amdgcn_global_load_lds(
        (const __attribute__((address_space(1))) void*)g,
        (__attribute__((address_space(3))) void*)l, 16, 0, 0);
}

// ---- weight transpose + cast: Wt[l][n][k] = (bf16) W[l][k][n] --------------
// 64(n) x 32(k) tiles; coalesced fp32 reads, one 16B bf16x8 store per thread.
__global__ __launch_bounds__(256) void transpose_cast(const float* __restrict__ W,
                                                      bf16* __restrict__ Wt,
                                                      int K, int Nm) {
    __shared__ float tile[64][33];
    const int l = blockIdx.z;
    const float* Wl = W + (size_t)l * K * Nm;
    bf16* Wtl = Wt + (size_t)l * K * Nm;
    const int n0 = blockIdx.x * 64, k0 = blockIdx.y * 32;
    const int t = threadIdx.x;
    const int tx = t & 63, ty = t >> 6;      // read: n = n0+tx, k = k0+ty+4i
#pragma unroll
    for (int i = 0; i < 8; ++i)
        tile[tx][ty + 4 * i] = Wl[(size_t)(k0 + ty + 4 * i) * Nm + n0 + tx];
    __syncthreads();
    const int nr = t >> 2, kq = (t & 3) * 8; // write: row n0+nr, 8 bf16 at k0+kq
    union { unsigned short s[8]; uint4 v; } o;
#pragma unroll
    for (int e = 0; e < 8; ++e)
        o.s[e] = f2b(tile[nr][kq + e]);
    *reinterpret_cast<uint4*>(&Wtl[(size_t)(n0 + nr) * K + k0 + kq]) = o.v;
}

// ---- elementwise fp32 -> bf16 ----------------------------------------------
__global__ __launch_bounds__(256) void cast_bf16_k(const float* __restrict__ in,
                                                   bf16* __restrict__ out, int n4) {
    int i = blockIdx.x * 256 + threadIdx.x;
    if (i >= n4) return;
    float4 v = reinterpret_cast<const float4*>(in)[i];
    ushort4 o = { f2b(v.x), f2b(v.y), f2b(v.z), f2b(v.w) };
    reinterpret_cast<ushort4*>(out)[i] = o;
}

// ---- 256x256 4-phase-per-K-tile GEMM with T2 swizzle ------------------------
// EPI: 1 = bias+gelu -> bf16 out; 3 = raw bf16 partials to Cout (splits 0,1)
// / Cout2 (splits 2,3); 4 = qkv: Q/K cols -> bias bf16 Cout, V cols
// (n0 >= 2048) -> bias + TRANSPOSED ushort4 into Cout2 (vtg layout, N=2048).
template <int EPI>
__global__ __launch_bounds__(512, 2) void gemm256p(const bf16* __restrict__ A,
                                                   const bf16* __restrict__ Bt,
                                                   const float* __restrict__ bias,
                                                   void* __restrict__ Cout,
                                                   void* __restrict__ Cout2,
                                                   int M, int Nm, int K,
                                                   int nbx, int ntiles, int Ktotal) {
    __shared__ bf16 As[2][256][64];   // 64 KB
    __shared__ bf16 Bs[2][256][64];   // 64 KB
    const int nwg = gridDim.x;
    int id = blockIdx.x;
    id = (id & 7) * (nwg >> 3) + (id >> 3);          // bijective: nwg % 8 == 0
    const int tile = id % ntiles, split = id / ntiles;
    const int m0 = (tile / nbx) * 256, n0 = (tile % nbx) * 256;
    const int kbase = split * K;
    const int t = threadIdx.x, lane = t & 63;
    const int w = t >> 6;
    const int wm = w >> 2, wn = w & 3;               // 2 x 4 wave grid
    const int lr = lane & 15, lg = lane >> 4;
    const int srowt = t >> 3;                        // staging row 0..63
    const int scol = (t & 7) * 8;                    // linear LDS chunk col
    const int gcol = (((t & 7) ^ ((t >> 3) & 7)) * 8);  // swizzled global col
    const bf16* Ag = A + (size_t)(m0 + srowt) * Ktotal + kbase + gcol;
    const bf16* Bg = Bt + (size_t)(n0 + srowt) * Ktotal + kbase + gcol;
    const int cidx0 = ((lg) ^ (lr & 7)) * 8;         // kk=0 read chunk
    const int cidx1 = ((4 + lg) ^ (lr & 7)) * 8;     // kk=1 read chunk

    f32x4 acc[8][4] = {};
    const int NT = K / 64;

#define STAGEH(h, kt, d)                                                         \
    {                                                                            \
        const size_t koff = (size_t)(kt) * 64;                                   \
        _Pragma("unroll")                                                        \
        for (int p = 0; p < 2; ++p) {                                            \
            const int roff = ((h) & 1) * 128 + p * 64;                           \
            if ((h) < 2)                                                         \
                gload_lds16(Ag + (size_t)roff * Ktotal + koff,                   \
                            &As[d][roff + srowt][scol]);                         \
            else                                                                 \
                gload_lds16(Bg + (size_t)roff * Ktotal + koff,                   \
                            &Bs[d][roff + srowt][scol]);                         \
        }                                                                        \
    }

    STAGEH(0, 0, 0); STAGEH(1, 0, 0); STAGEH(2, 0, 0); STAGEH(3, 0, 0);

    for (int kt = 0; kt < NT; ++kt) {
        const int d = kt & 1;
        const bool more = (kt + 1) < NT;
        asm volatile("s_waitcnt vmcnt(0)" ::: "memory");
        __builtin_amdgcn_sched_barrier(0);
        __builtin_amdgcn_s_barrier();
        __builtin_amdgcn_sched_barrier(0);

        bf16x8 a[8], b[4];

        // ---- phase 0: kk=0, n={0,1} ----
        if (more) STAGEH(0, kt + 1, d ^ 1);
#pragma unroll
        for (int m = 0; m < 8; ++m)
            a[m] = *reinterpret_cast<const bf16x8*>(&As[d][wm * 128 + m * 16 + lr][cidx0]);
        b[0] = *reinterpret_cast<const bf16x8*>(&Bs[d][wn * 64 + lr][cidx0]);
        b[1] = *reinterpret_cast<const bf16x8*>(&Bs[d][wn * 64 + 16 + lr][cidx0]);
        __builtin_amdgcn_sched_barrier(0);
        __builtin_amdgcn_s_barrier();
        asm volatile("s_waitcnt lgkmcnt(0)" ::: "memory");
        __builtin_amdgcn_sched_barrier(0);
        __builtin_amdgcn_s_setprio(1);
#pragma unroll
        for (int m = 0; m < 8; ++m) {
            acc[m][0] = __builtin_amdgcn_mfma_f32_16x16x32_bf16(a[m], b[0], acc[m][0], 0, 0, 0);
            acc[m][1] = __builtin_amdgcn_mfma_f32_16x16x32_bf16(a[m], b[1], acc[m][1], 0, 0, 0);
        }
        __builtin_amdgcn_s_setprio(0);
        __builtin_amdgcn_sched_barrier(0);

        // ---- phase 1: kk=0, n={2,3} ----
        if (more) STAGEH(1, kt + 1, d ^ 1);
        b[2] = *reinterpret_cast<const bf16x8*>(&Bs[d][wn * 64 + 32 + lr][cidx0]);
        b[3] = *reinterpret_cast<const bf16x8*>(&Bs[d][wn * 64 + 48 + lr][cidx0]);
        __builtin_amdgcn_sched_barrier(0);
        __builtin_amdgcn_s_barrier();
        asm volatile("s_waitcnt lgkmcnt(0)" ::: "memory");
        __builtin_amdgcn_sched_barrier(0);
        __builtin_amdgcn_s_setprio(1);
#pragma unroll
        for (int m = 0; m < 8; ++m) {
            acc[m][2] = __builtin_amdgcn_mfma_f32_16x16x32_bf16(a[m], b[2], acc[m][2], 0, 0, 0);
            acc[m][3] = __builtin_amdgcn_mfma_f32_16x16x32_bf16(a[m], b[3], acc[m][3], 0, 0, 0);
        }
        __builtin_amdgcn_s_setprio(0);
        __builtin_amdgcn_sched_barrier(0);

        // ---- phase 2: kk=1, n={0,1} ----
        if (more) STAGEH(2, kt + 1, d ^ 1);
#pragma unroll
        for (int m = 0; m < 8; ++m)
            a[m] = *reinterpret_cast<const bf16x8*>(&As[d][wm * 128 + m * 16 + lr][cidx1]);
        b[0] = *reinterpret_cast<const bf16x8*>(&Bs[d][wn * 64 + lr][cidx1]);
        b[1] = *reinterpret_cast<const bf16x8*>(&Bs[d][wn * 64 + 16 + lr][cidx1]);
        __builtin_amdgcn_sched_barrier(0);
        __builtin_amdgcn_s_barrier();
        asm volatile("s_waitcnt lgkmcnt(0)" ::: "memory");
        __builtin_amdgcn_sched_barrier(0);
        __builtin_amdgcn_s_setprio(1);
#pragma unroll
        for (int m = 0; m < 8; ++m) {
            acc[m][0] = __builtin_amdgcn_mfma_f32_16x16x32_bf16(a[m], b[0], acc[m][0], 0, 0, 0);
            acc[m][1] = __builtin_amdgcn_mfma_f32_16x16x32_bf16(a[m], b[1], acc[m][1], 0, 0, 0);
        }
        __builtin_amdgcn_s_setprio(0);
        __builtin_amdgcn_sched_barrier(0);

        // ---- phase 3: kk=1, n={2,3} ----
        if (more) STAGEH(3, kt + 1, d ^ 1);
        b[2] = *reinterpret_cast<const bf16x8*>(&Bs[d][wn * 64 + 32 + lr][cidx1]);
        b[3] = *reinterpret_cast<const bf16x8*>(&Bs[d][wn * 64 + 48 + lr][cidx1]);
        __builtin_amdgcn_sched_barrier(0);
        __builtin_amdgcn_s_barrier();
        asm volatile("s_waitcnt lgkmcnt(0)" ::: "memory");
        __builtin_amdgcn_sched_barrier(0);
        __builtin_amdgcn_s_setprio(1);
#pragma unroll
        for (int m = 0; m < 8; ++m) {
            acc[m][2] = __builtin_amdgcn_mfma_f32_16x16x32_bf16(a[m], b[2], acc[m][2], 0, 0, 0);
            acc[m][3] = __builtin_amdgcn_mfma_f32_16x16x32_bf16(a[m], b[3], acc[m][3], 0, 0, 0);
        }
        __builtin_amdgcn_s_setprio(0);
        __builtin_amdgcn_sched_barrier(0);
    }
#undef STAGEH

    if (EPI == 3) {
        bf16* outp = (split < 2)
            ? (bf16*)Cout + (size_t)split * M * Nm
            : (bf16*)Cout2 + (size_t)(split - 2) * M * Nm;
#pragma unroll
        for (int n = 0; n < 4; ++n) {
            const int col = n0 + wn * 64 + n * 16 + lr;
#pragma unroll
            for (int m = 0; m < 8; ++m) {
                const int row = m0 + wm * 128 + m * 16 + lg * 4;
#pragma unroll
                for (int j = 0; j < 4; ++j)
                    outp[(size_t)(row + j) * Nm + col] = __float2bfloat16(acc[m][n][j]);
            }
        }
    } else if (EPI == 4 && n0 >= 2048) {
        // V tile: write transposed into vtg[(b*1024 + (col-2048))][n], N=2048
#pragma unroll
        for (int n = 0; n < 4; ++n) {
            const int col = n0 + wn * 64 + n * 16 + lr;
            const float bc = bias[col];
            const int vcol = col - 2048;
#pragma unroll
            for (int m = 0; m < 8; ++m) {
                const int row = m0 + wm * 128 + m * 16 + lg * 4;
                const int b = row >> 11, nn = row & 2047;
                ushort4 o = { f2b(acc[m][n][0] + bc), f2b(acc[m][n][1] + bc),
                              f2b(acc[m][n][2] + bc), f2b(acc[m][n][3] + bc) };
                *reinterpret_cast<ushort4*>(
                    (bf16*)Cout2 + ((size_t)(b * 1024 + vcol)) * 2048 + nn) = o;
            }
        }
    } else {
#pragma unroll
        for (int n = 0; n < 4; ++n) {
            const int col = n0 + wn * 64 + n * 16 + lr;
            const float bc = bias[col];
#pragma unroll
            for (int m = 0; m < 8; ++m) {
                const int row = m0 + wm * 128 + m * 16 + lg * 4;
#pragma unroll
                for (int j = 0; j < 4; ++j) {
                    float v = acc[m][n][j] + bc;
                    if (EPI == 1) v = gelu_fast(v);
                    reinterpret_cast<bf16*>(Cout)[(size_t)(row + j) * Nm + col] = __float2bfloat16(v);
                }
            }
        }
    }
}

// ---- flash attention, swapped-operand, QBLK=128, fixed-shift softmax -------
__global__ __launch_bounds__(256) void attn_fwd(const bf16* __restrict__ qkv,
                                                const bf16* __restrict__ vtg,
                                                bf16* __restrict__ o, int N) {
    __shared__ bf16 Ks[2][64][72];   // K tiles [kv][dh], padded
    __shared__ bf16 Vs[2][64][72];   // V^T tiles [dh][kv], padded
    __shared__ bf16 Ps[4][32][72];   // per-wave P [q][kv], padded
    const int nwg = gridDim.x, nbx = N / 128;
    int id = blockIdx.x;
    id = (id & 7) * (nwg >> 3) + (id >> 3);  // XCD-chunked
    const int bh = id / nbx, b = bh >> 4, h = bh & 15;
    const int q0 = (id % nbx) * 128;
    const int t = threadIdx.x, w = t >> 6, lane = t & 63;
    const int lr = lane & 15, lg = lane >> 4;
    const bf16* base = qkv + (size_t)b * N * 3072;
    const bf16* vbase = vtg + (size_t)bh * 64 * N;

    bf16x8 qf[2][2];
#pragma unroll
    for (int rb = 0; rb < 2; ++rb) {
        const bf16* qp = base + (size_t)(q0 + w * 32 + rb * 16 + lr) * 3072 + h * 64 + lg * 8;
        qf[rb][0] = *reinterpret_cast<const bf16x8*>(qp);
        qf[rb][1] = *reinterpret_cast<const bf16x8*>(qp + 32);
    }

    float lrow[2] = { 0.f, 0.f };
    f32x4 oacc[2][4] = {};
    const float scale2 = 0.03125f * 1.44269504088896340736f;  // embedDim^-0.5 * log2(e)
    const float MSHIFT = 16.0f;  // fixed softmax shift (exp2 domain); cancels in 1/lrow
    const int srow = t >> 2, scolb = (t & 3) * 8;

    const bf16* kptr = base + (size_t)srow * 3072 + 1024 + h * 64 + scolb;
    const bf16* vptr = vbase + (size_t)srow * N + scolb;

    uint4 k0 = *reinterpret_cast<const uint4*>(kptr);
    uint4 k1 = *reinterpret_cast<const uint4*>(kptr + 32);
    uint4 v0 = *reinterpret_cast<const uint4*>(vptr);
    uint4 v1 = *reinterpret_cast<const uint4*>(vptr + 32);
    *reinterpret_cast<uint4*>(&Ks[0][srow][scolb])      = k0;
    *reinterpret_cast<uint4*>(&Ks[0][srow][scolb + 32]) = k1;
    *reinterpret_cast<uint4*>(&Vs[0][srow][scolb])      = v0;
    *reinterpret_cast<uint4*>(&Vs[0][srow][scolb + 32]) = v1;

    int cur = 0;
    for (int kv0 = 0; kv0 < N; kv0 += 64) {
        __syncthreads();
        const bool more = (kv0 + 64) < N;
        if (more) {
            const bf16* kn = kptr + (size_t)(kv0 + 64) * 3072;
            const bf16* vn = vptr + (kv0 + 64);
            k0 = *reinterpret_cast<const uint4*>(kn);
            k1 = *reinterpret_cast<const uint4*>(kn + 32);
            v0 = *reinterpret_cast<const uint4*>(vn);
            v1 = *reinterpret_cast<const uint4*>(vn + 32);
        }
        __builtin_amdgcn_sched_barrier(0);

        f32x4 st[2][4] = {};
#pragma unroll
        for (int f = 0; f < 2; ++f)
#pragma unroll
            for (int c = 0; c < 4; ++c) {
                bf16x8 ka = *reinterpret_cast<const bf16x8*>(&Ks[cur][c * 16 + lr][f * 32 + lg * 8]);
                st[0][c] = __builtin_amdgcn_mfma_f32_16x16x32_bf16(ka, qf[0][f], st[0][c], 0, 0, 0);
                st[1][c] = __builtin_amdgcn_mfma_f32_16x16x32_bf16(ka, qf[1][f], st[1][c], 0, 0, 0);
            }

        // fixed-shift softmax: P = exp2(s*scale2 - MSHIFT); shift cancels in 1/lrow
#pragma unroll
        for (int rb = 0; rb < 2; ++rb) {
            float p[4][4];
            float psum = 0.f;
#pragma unroll
            for (int c = 0; c < 4; ++c)
#pragma unroll
                for (int j = 0; j < 4; ++j) {
                    p[c][j] = __builtin_amdgcn_exp2f(fmaf(st[rb][c][j], scale2, -MSHIFT));
                    psum += p[c][j];
                }
            psum += __shfl_xor(psum, 16, 64);
            psum += __shfl_xor(psum, 32, 64);
            lrow[rb] += psum;
#pragma unroll
            for (int c = 0; c < 4; ++c) {
                uint2 pr = { pack_bf16_trunc(p[c][0], p[c][1]),
                             pack_bf16_trunc(p[c][2], p[c][3]) };
                *reinterpret_cast<uint2*>(&Ps[w][rb * 16 + lr][c * 16 + lg * 4]) = pr;
            }
        }
        asm volatile("s_waitcnt lgkmcnt(0)" ::: "memory");
        __builtin_amdgcn_sched_barrier(0);

#pragma unroll
        for (int f = 0; f < 2; ++f) {
            bf16x8 pb0 = *reinterpret_cast<const bf16x8*>(&Ps[w][lr][f * 32 + lg * 8]);
            bf16x8 pb1 = *reinterpret_cast<const bf16x8*>(&Ps[w][16 + lr][f * 32 + lg * 8]);
#pragma unroll
            for (int c = 0; c < 4; ++c) {
                bf16x8 va = *reinterpret_cast<const bf16x8*>(&Vs[cur][c * 16 + lr][f * 32 + lg * 8]);
                oacc[0][c] = __builtin_amdgcn_mfma_f32_16x16x32_bf16(va, pb0, oacc[0][c], 0, 0, 0);
                oacc[1][c] = __builtin_amdgcn_mfma_f32_16x16x32_bf16(va, pb1, oacc[1][c], 0, 0, 0);
            }
        }

        if (more) {
            asm volatile("s_waitcnt vmcnt(0)" ::: "memory");
            __builtin_amdgcn_sched_barrier(0);
            *reinterpret_cast<uint4*>(&Ks[cur ^ 1][srow][scolb])      = k0;
            *reinterpret_cast<uint4*>(&Ks[cur ^ 1][srow][scolb + 32]) = k1;
            *reinterpret_cast<uint4*>(&Vs[cur ^ 1][srow][scolb])      = v0;
            *reinterpret_cast<uint4*>(&Vs[cur ^ 1][srow][scolb + 32]) = v1;
        }
        cur ^= 1;
    }

    // O^T layout: col q = lr, row d = 16c + 4lg + j -> ushort4 stores (bf16)
#pragma unroll
    for (int rb = 0; rb < 2; ++rb) {
        const float linv = 1.f / lrow[rb];
        bf16* op = o + ((size_t)b * N + q0 + w * 32 + rb * 16 + lr) * 1024 + h * 64;
#pragma unroll
        for (int c = 0; c < 4; ++c) {
            ushort4 v = { f2b(oacc[rb][c][0] * linv), f2b(oacc[rb][c][1] * linv),
                          f2b(oacc[rb][c][2] * linv), f2b(oacc[rb][c][3] * linv) };
            *reinterpret_cast<ushort4*>(op + c * 16 + lg * 4) = v;
        }
    }
}

// ---- LN1: h = LN(o + x), o bf16, x bf16 (or fp32 layer 0); writes hb bf16 --
__global__ __launch_bounds__(256) void ln_res(const bf16* __restrict__ a,
                                              const float* __restrict__ r32,
                                              const bf16* __restrict__ r16,
                                              const float* __restrict__ g,
                                              const float* __restrict__ be,
                                              bf16* __restrict__ yb) {
    const int row = blockIdx.x, t = threadIdx.x;
    ushort4 va = reinterpret_cast<const ushort4*>(a + (size_t)row * 1024)[t];
    float v0 = b2f(va.x), v1 = b2f(va.y), v2 = b2f(va.z), v3 = b2f(va.w);
    if (r32) {
        float4 vr = reinterpret_cast<const float4*>(r32 + (size_t)row * 1024)[t];
        v0 += vr.x; v1 += vr.y; v2 += vr.z; v3 += vr.w;
    } else {
        ushort4 vr = reinterpret_cast<const ushort4*>(r16 + (size_t)row * 1024)[t];
        v0 += b2f(vr.x); v1 += b2f(vr.y); v2 += b2f(vr.z); v3 += b2f(vr.w);
    }
    float s1 = v0 + v1 + v2 + v3;
    float s2 = v0 * v0 + v1 * v1 + v2 * v2 + v3 * v3;
#pragma unroll
    for (int m = 1; m < 64; m <<= 1) {
        s1 += __shfl_xor(s1, m, 64);
        s2 += __shfl_xor(s2, m, 64);
    }
    __shared__ float ws1[4], ws2[4];
    if ((t & 63) == 0) { ws1[t >> 6] = s1; ws2[t >> 6] = s2; }
    __syncthreads();
    s1 = ws1[0] + ws1[1] + ws1[2] + ws1[3];
    s2 = ws2[0] + ws2[1] + ws2[2] + ws2[3];
    const float mean = s1 * (1.f / 1024.f);
    const float var = s2 * (1.f / 1024.f) - mean * mean;
    const float rstd = rsqrtf(var + 1e-5f);
    float4 gg = reinterpret_cast<const float4*>(g)[t];
    float4 bb = reinterpret_cast<const float4*>(be)[t];
    float o0 = (v0 - mean) * rstd * gg.x + bb.x;
    float o1 = (v1 - mean) * rstd * gg.y + bb.y;
    float o2 = (v2 - mean) * rstd * gg.z + bb.z;
    float o3 = (v3 - mean) * rstd * gg.w + bb.w;
    ushort4 ob = { f2b(o0), f2b(o1), f2b(o2), f2b(o3) };
    reinterpret_cast<ushort4*>(yb + (size_t)row * 1024)[t] = ob;
}

// ---- LN2: f2 = gelu(sum 4 bf16 partials + b2); x = LN(f2 + h), h bf16 ------
__global__ __launch_bounds__(256) void ln_res_red4(const bf16* __restrict__ p0,
                                                   const bf16* __restrict__ p2,
                                                   const float* __restrict__ bias,
                                                   const bf16* __restrict__ r,
                                                   const float* __restrict__ g,
                                                   const float* __restrict__ be,
                                                   float* __restrict__ y,
                                                   bf16* __restrict__ yb,
                                                   size_t stride) {
    const int row = blockIdx.x, t = threadIdx.x;
    const size_t off = (size_t)row * 1024 + t * 4;
    float4 bb4 = reinterpret_cast<const float4*>(bias)[t];
    float s0 = bb4.x, s1v = bb4.y, s2v = bb4.z, s3 = bb4.w;
#pragma unroll
    for (int k = 0; k < 2; ++k) {
        ushort4 va = *reinterpret_cast<const ushort4*>(p0 + k * stride + off);
        s0 += b2f(va.x); s1v += b2f(va.y); s2v += b2f(va.z); s3 += b2f(va.w);
        ushort4 vb = *reinterpret_cast<const ushort4*>(p2 + k * stride + off);
        s0 += b2f(vb.x); s1v += b2f(vb.y); s2v += b2f(vb.z); s3 += b2f(vb.w);
    }
    ushort4 vr = *reinterpret_cast<const ushort4*>(r + off);
    float v0 = gelu_fast(s0) + b2f(vr.x);
    float v1 = gelu_fast(s1v) + b2f(vr.y);
    float v2 = gelu_fast(s2v) + b2f(vr.z);
    float v3 = gelu_fast(s3) + b2f(vr.w);
    float s1 = v0 + v1 + v2 + v3;
    float s2 = v0 * v0 + v1 * v1 + v2 * v2 + v3 * v3;
#pragma unroll
    for (int m = 1; m < 64; m <<= 1) {
        s1 += __shfl_xor(s1, m, 64);
        s2 += __shfl_xor(s2, m, 64);
    }
    __shared__ float ws1[4], ws2[4];
    if ((t & 63) == 0) { ws1[t >> 6] = s1; ws2[t >> 6] = s2; }
    __syncthreads();
    s1 = ws1[0] + ws1[1] + ws1[2] + ws1[3];
    s2 = ws2[0] + ws2[1] + ws2[2] + ws2[3];
    const float mean = s1 * (1.f / 1024.f);
    const float var = s2 * (1.f / 1024.f) - mean * mean;
    const float rstd = rsqrtf(var + 1e-5f);
    float4 gg = reinterpret_cast<const float4*>(g)[t];
    float4 bb = reinterpret_cast<const float4*>(be)[t];
    float o0 = (v0 - mean) * rstd * gg.x + bb.x;
    float o1 = (v1 - mean) * rstd * gg.y + bb.y;
    float o2 = (v2 - mean) * rstd * gg.z + bb.z;
    float o3 = (v3 - mean) * rstd * gg.w + bb.w;
    if (y) {
        float4 out = { o0, o1, o2, o3 };
        reinterpret_cast<float4*>(y + (size_t)row * 1024)[t] = out;
    }
    ushort4 ob = { f2b(o0), f2b(o1), f2b(o2), f2b(o3) };
    reinterpret_cast<ushort4*>(yb + (size_t)row * 1024)[t] = ob;
}

// ---------------------------------------------------------------------------
extern "C" void kernel_launch(void* const* d_in, const int* in_sizes, int n_in,
                              void* d_out, int out_size, void* d_ws, size_t ws_size,
                              hipStream_t stream) {
    const float* x_in = (const float*)d_in[0];
    const float* Wqkv = (const float*)d_in[1];
    const float* bqkv = (const float*)d_in[2];
    const float* W1   = (const float*)d_in[3];
    const float* b1   = (const float*)d_in[4];
    const float* W2   = (const float*)d_in[5];
    const float* b2   = (const float*)d_in[6];
    const float* g1   = (const float*)d_in[7];
    const float* be1  = (const float*)d_in[8];
    const float* g2   = (const float*)d_in[9];
    const float* be2  = (const float*)d_in[10];

    const int Bv = 2, N = 2048, L = 4, Hh = 16;
    const int R = Bv * N;  // 4096 token rows

    char* p = (char*)d_ws;
    auto alloc = [&](size_t bytes) { char* r = p; p += (bytes + 255) & ~(size_t)255; return r; };
    bf16*  Wqkvt = (bf16*)alloc((size_t)L * 3072 * 1024 * 2);
    bf16*  W1t   = (bf16*)alloc((size_t)L * 4096 * 1024 * 2);
    bf16*  W2t   = (bf16*)alloc((size_t)L * 1024 * 4096 * 2);
    bf16*  xb    = (bf16*)alloc((size_t)R * 1024 * 2);
    bf16*  qkvb  = (bf16*)alloc((size_t)R * 3072 * 2);
    float* obuf  = (float*)alloc((size_t)R * 1024 * 4);   // region: attn bf16 out + part0
    float* hbuf  = (float*)alloc((size_t)R * 1024 * 4);   // region: vtg
    bf16*  hb    = (bf16*)alloc((size_t)R * 1024 * 2);
    bf16*  f1b   = (bf16*)alloc((size_t)R * 4096 * 2);
    bf16*  vtg   = (bf16*)hbuf;   // 8.4MB V^T
    bf16*  ob    = (bf16*)obuf;   // attn bf16 output
    bf16*  part0 = (bf16*)obuf;   // split-K partials 0,1 (dead after LN1)
    bf16*  part2 = (bf16*)qkvb;   // split-K partials 2,3 (dead after attn)

    transpose_cast<<<dim3(3072 / 64, 1024 / 32, L), 256, 0, stream>>>(Wqkv, Wqkvt, 1024, 3072);
    transpose_cast<<<dim3(4096 / 64, 1024 / 32, L), 256, 0, stream>>>(W1, W1t, 1024, 4096);
    transpose_cast<<<dim3(1024 / 64, 4096 / 32, L), 256, 0, stream>>>(W2, W2t, 4096, 1024);
    cast_bf16_k<<<(R * 1024 / 4 + 255) / 256, 256, 0, stream>>>(x_in, xb, R * 1024 / 4);

    for (int l = 0; l < L; ++l) {
        // qkv = x @ Wqkv + bqkv; Q/K -> qkvb, V -> transposed vtg (4-phase EPI4)
        gemm256p<4><<<(R / 256) * (3072 / 256), 512, 0, stream>>>(
            xb, Wqkvt + (size_t)l * 3072 * 1024, bqkv + l * 3072, qkvb, vtg,
            R, 3072, 1024, 3072 / 256, (R / 256) * (3072 / 256), 1024);
        // o = softmax(q k^T / 32) v -> bf16   (QBLK=128, 512 blocks)
        attn_fwd<<<(N / 128) * (Bv * Hh), 256, 0, stream>>>(qkvb, vtg, ob, N);
        // h = LN(o + x) -> hb bf16  (residual: fp32 x_in layer 0, else bf16 xb)
        ln_res<<<R, 256, 0, stream>>>(ob, l == 0 ? x_in : nullptr,
                                      l == 0 ? nullptr : xb,
                                      g1 + l * 1024, be1 + l * 1024, hb);
        // f1 = gelu(h @ W1 + b1) -> bf16  (4-phase pipelined + swizzle)
        gemm256p<1><<<(R / 256) * (4096 / 256), 512, 0, stream>>>(
            hb, W1t + (size_t)l * 4096 * 1024, b1 + l * 4096, f1b, nullptr,
            R, 4096, 1024, 4096 / 256, (R / 256) * (4096 / 256), 1024);
        // f2 partials: f1 @ W2 split-K=4 -> bf16 into part0 (s0,s1) / part2 (s2,s3)
        gemm256p<3><<<(R / 256) * (1024 / 256) * 4, 512, 0, stream>>>(
            f1b, W2t + (size_t)l * 1024 * 4096, nullptr, part0, part2,
            R, 1024, 1024, 1024 / 256, (R / 256) * (1024 / 256), 4096);
        // x = LN(gelu(sum partials + b2) + h) -> xb bf16 (+ fp32 d_out last layer)
        ln_res_red4<<<R, 256, 0, stream>>>(part0, part2, b2 + l * 1024, hb,
                                           g2 + l * 1024, be2 + l * 1024,
                                           l == L - 1 ? (float*)d_out : nullptr,
                                           xb, (size_t)R * 1024);
    }
}

// Round 21
// 969.292 us; speedup vs baseline: 1.0039x; 1.0039x over previous
//
#include <hip/hip_runtime.h>
#include <hip/hip_bf16.h>
#include <cmath>

// ---------------------------------------------------------------------------
// TextEncoder: 4-layer post-LN transformer, B=2 N=2048 D=1024 H=16 dh=64 FF=4096
// R18: (1) attn P-pack -> bit-truncation (3 ops vs ~10 for RNE f2b; psum stays
// fp32-exact, 1/sum normalization tolerates the 2^-8 truncation). (2) weight
// transpose_cast rewritten: 64x32 tiles, coalesced float reads, 16B bf16x8
// stores (was scalar 2B). Rest unchanged from R17.
// ---------------------------------------------------------------------------

typedef __attribute__((ext_vector_type(8))) short bf16x8;
typedef __attribute__((ext_vector_type(4))) float f32x4;
typedef __hip_bfloat16 bf16;

#define DEV static __device__ __forceinline__

DEV unsigned short f2b(float f) {
    bf16 h = __float2bfloat16(f);
    return *reinterpret_cast<unsigned short*>(&h);
}

// truncation pack: two non-negative floats -> packed bf16 pair (lo | hi<<16)
DEV unsigned int pack_bf16_trunc(float lo, float hi) {
    unsigned int ulo = *reinterpret_cast<unsigned int*>(&lo);
    unsigned int uhi = *reinterpret_cast<unsigned int*>(&hi);
    return (uhi & 0xFFFF0000u) | (ulo >> 16);
}

DEV float b2f(unsigned short u) {
    unsigned int x = ((unsigned int)u) << 16;
    return *reinterpret_cast<float*>(&x);
}

// tanh-form gelu: max abs deviation from exact ~1e-3, ~10 VALU ops.
DEV float gelu_fast(float x) {
    float u = 0.7978845608028654f * fmaf(0.044715f * x, x * x, x);
    u = fminf(fmaxf(u, -15.f), 15.f);
    float t = __builtin_amdgcn_exp2f(u * 2.8853900817779268f);
    float th = (t - 1.0f) * __builtin_amdgcn_rcpf(t + 1.0f);
    return 0.5f * x * (1.0f + th);
}

DEV void gload_lds16(const bf16* g, bf16* l) {
    __builtin_amdgcn_global_load_lds(
        (const __attribute__((address_space(1))) void*)g,
        (__attribute__((address_space(3))) void*)l, 16, 0, 0);
}

// ---- weight transpose + cast: Wt[l][n][k] = (bf16) W[l][k][n] --------------
// 64(n) x 32(k) tiles; coalesced fp32 reads, one 16B bf16x8 store per thread.
__global__ __launch_bounds__(256) void transpose_cast(const float* __restrict__ W,
                                                      bf16* __restrict__ Wt,
                                                      int K, int Nm) {
    __shared__ float tile[64][33];
    const int l = blockIdx.z;
    const float* Wl = W + (size_t)l * K * Nm;
    bf16* Wtl = Wt + (size_t)l * K * Nm;
    const int n0 = blockIdx.x * 64, k0 = blockIdx.y * 32;
    const int t = threadIdx.x;
    const int tx = t & 63, ty = t >> 6;      // read: n = n0+tx, k = k0+ty+4i
#pragma unroll
    for (int i = 0; i < 8; ++i)
        tile[tx][ty + 4 * i] = Wl[(size_t)(k0 + ty + 4 * i) * Nm + n0 + tx];
    __syncthreads();
    const int nr = t >> 2, kq = (t & 3) * 8; // write: row n0+nr, 8 bf16 at k0+kq
    union { unsigned short s[8]; uint4 v; } o;
#pragma unroll
    for (int e = 0; e < 8; ++e)
        o.s[e] = f2b(tile[nr][kq + e]);
    *reinterpret_cast<uint4*>(&Wtl[(size_t)(n0 + nr) * K + k0 + kq]) = o.v;
}

// ---- elementwise fp32 -> bf16 ----------------------------------------------
__global__ __launch_bounds__(256) void cast_bf16_k(const float* __restrict__ in,
                                                   bf16* __restrict__ out, int n4) {
    int i = blockIdx.x * 256 + threadIdx.x;
    if (i >= n4) return;
    float4 v = reinterpret_cast<const float4*>(in)[i];
    ushort4 o = { f2b(v.x), f2b(v.y), f2b(v.z), f2b(v.w) };
    reinterpret_cast<ushort4*>(out)[i] = o;
}

// ---- 256x256 4-phase-per-K-tile GEMM with T2 swizzle ------------------------
// EPI: 1 = bias+gelu -> bf16 out; 3 = raw bf16 partials to Cout (splits 0,1)
// / Cout2 (splits 2,3); 4 = qkv: Q/K cols -> bias bf16 Cout, V cols
// (n0 >= 2048) -> bias + TRANSPOSED ushort4 into Cout2 (vtg layout, N=2048).
template <int EPI>
__global__ __launch_bounds__(512, 2) void gemm256p(const bf16* __restrict__ A,
                                                   const bf16* __restrict__ Bt,
                                                   const float* __restrict__ bias,
                                                   void* __restrict__ Cout,
                                                   void* __restrict__ Cout2,
                                                   int M, int Nm, int K,
                                                   int nbx, int ntiles, int Ktotal) {
    __shared__ bf16 As[2][256][64];   // 64 KB
    __shared__ bf16 Bs[2][256][64];   // 64 KB
    const int nwg = gridDim.x;
    int id = blockIdx.x;
    id = (id & 7) * (nwg >> 3) + (id >> 3);          // bijective: nwg % 8 == 0
    const int tile = id % ntiles, split = id / ntiles;
    const int m0 = (tile / nbx) * 256, n0 = (tile % nbx) * 256;
    const int kbase = split * K;
    const int t = threadIdx.x, lane = t & 63;
    const int w = t >> 6;
    const int wm = w >> 2, wn = w & 3;               // 2 x 4 wave grid
    const int lr = lane & 15, lg = lane >> 4;
    const int srowt = t >> 3;                        // staging row 0..63
    const int scol = (t & 7) * 8;                    // linear LDS chunk col
    const int gcol = (((t & 7) ^ ((t >> 3) & 7)) * 8);  // swizzled global col
    const bf16* Ag = A + (size_t)(m0 + srowt) * Ktotal + kbase + gcol;
    const bf16* Bg = Bt + (size_t)(n0 + srowt) * Ktotal + kbase + gcol;
    const int cidx0 = ((lg) ^ (lr & 7)) * 8;         // kk=0 read chunk
    const int cidx1 = ((4 + lg) ^ (lr & 7)) * 8;     // kk=1 read chunk

    f32x4 acc[8][4] = {};
    const int NT = K / 64;

#define STAGEH(h, kt, d)                                                         \
    {                                                                            \
        const size_t koff = (size_t)(kt) * 64;                                   \
        _Pragma("unroll")                                                        \
        for (int p = 0; p < 2; ++p) {                                            \
            const int roff = ((h) & 1) * 128 + p * 64;                           \
            if ((h) < 2)                                                         \
                gload_lds16(Ag + (size_t)roff * Ktotal + koff,                   \
                            &As[d][roff + srowt][scol]);                         \
            else                                                                 \
                gload_lds16(Bg + (size_t)roff * Ktotal + koff,                   \
                            &Bs[d][roff + srowt][scol]);                         \
        }                                                                        \
    }

    STAGEH(0, 0, 0); STAGEH(1, 0, 0); STAGEH(2, 0, 0); STAGEH(3, 0, 0);

    for (int kt = 0; kt < NT; ++kt) {
        const int d = kt & 1;
        const bool more = (kt + 1) < NT;
        asm volatile("s_waitcnt vmcnt(0)" ::: "memory");
        __builtin_amdgcn_sched_barrier(0);
        __builtin_amdgcn_s_barrier();
        __builtin_amdgcn_sched_barrier(0);

        bf16x8 a[8], b[4];

        // ---- phase 0: kk=0, n={0,1} ----
        if (more) STAGEH(0, kt + 1, d ^ 1);
#pragma unroll
        for (int m = 0; m < 8; ++m)
            a[m] = *reinterpret_cast<const bf16x8*>(&As[d][wm * 128 + m * 16 + lr][cidx0]);
        b[0] = *reinterpret_cast<const bf16x8*>(&Bs[d][wn * 64 + lr][cidx0]);
        b[1] = *reinterpret_cast<const bf16x8*>(&Bs[d][wn * 64 + 16 + lr][cidx0]);
        __builtin_amdgcn_sched_barrier(0);
        __builtin_amdgcn_s_barrier();
        asm volatile("s_waitcnt lgkmcnt(0)" ::: "memory");
        __builtin_amdgcn_sched_barrier(0);
        __builtin_amdgcn_s_setprio(1);
#pragma unroll
        for (int m = 0; m < 8; ++m) {
            acc[m][0] = __builtin_amdgcn_mfma_f32_16x16x32_bf16(a[m], b[0], acc[m][0], 0, 0, 0);
            acc[m][1] = __builtin_amdgcn_mfma_f32_16x16x32_bf16(a[m], b[1], acc[m][1], 0, 0, 0);
        }
        __builtin_amdgcn_s_setprio(0);
        __builtin_amdgcn_sched_barrier(0);

        // ---- phase 1: kk=0, n={2,3} ----
        if (more) STAGEH(1, kt + 1, d ^ 1);
        b[2] = *reinterpret_cast<const bf16x8*>(&Bs[d][wn * 64 + 32 + lr][cidx0]);
        b[3] = *reinterpret_cast<const bf16x8*>(&Bs[d][wn * 64 + 48 + lr][cidx0]);
        __builtin_amdgcn_sched_barrier(0);
        __builtin_amdgcn_s_barrier();
        asm volatile("s_waitcnt lgkmcnt(0)" ::: "memory");
        __builtin_amdgcn_sched_barrier(0);
        __builtin_amdgcn_s_setprio(1);
#pragma unroll
        for (int m = 0; m < 8; ++m) {
            acc[m][2] = __builtin_amdgcn_mfma_f32_16x16x32_bf16(a[m], b[2], acc[m][2], 0, 0, 0);
            acc[m][3] = __builtin_amdgcn_mfma_f32_16x16x32_bf16(a[m], b[3], acc[m][3], 0, 0, 0);
        }
        __builtin_amdgcn_s_setprio(0);
        __builtin_amdgcn_sched_barrier(0);

        // ---- phase 2: kk=1, n={0,1} ----
        if (more) STAGEH(2, kt + 1, d ^ 1);
#pragma unroll
        for (int m = 0; m < 8; ++m)
            a[m] = *reinterpret_cast<const bf16x8*>(&As[d][wm * 128 + m * 16 + lr][cidx1]);
        b[0] = *reinterpret_cast<const bf16x8*>(&Bs[d][wn * 64 + lr][cidx1]);
        b[1] = *reinterpret_cast<const bf16x8*>(&Bs[d][wn * 64 + 16 + lr][cidx1]);
        __builtin_amdgcn_sched_barrier(0);
        __builtin_amdgcn_s_barrier();
        asm volatile("s_waitcnt lgkmcnt(0)" ::: "memory");
        __builtin_amdgcn_sched_barrier(0);
        __builtin_amdgcn_s_setprio(1);
#pragma unroll
        for (int m = 0; m < 8; ++m) {
            acc[m][0] = __builtin_amdgcn_mfma_f32_16x16x32_bf16(a[m], b[0], acc[m][0], 0, 0, 0);
            acc[m][1] = __builtin_amdgcn_mfma_f32_16x16x32_bf16(a[m], b[1], acc[m][1], 0, 0, 0);
        }
        __builtin_amdgcn_s_setprio(0);
        __builtin_amdgcn_sched_barrier(0);

        // ---- phase 3: kk=1, n={2,3} ----
        if (more) STAGEH(3, kt + 1, d ^ 1);
        b[2] = *reinterpret_cast<const bf16x8*>(&Bs[d][wn * 64 + 32 + lr][cidx1]);
        b[3] = *reinterpret_cast<const bf16x8*>(&Bs[d][wn * 64 + 48 + lr][cidx1]);
        __builtin_amdgcn_sched_barrier(0);
        __builtin_amdgcn_s_barrier();
        asm volatile("s_waitcnt lgkmcnt(0)" ::: "memory");
        __builtin_amdgcn_sched_barrier(0);
        __builtin_amdgcn_s_setprio(1);
#pragma unroll
        for (int m = 0; m < 8; ++m) {
            acc[m][2] = __builtin_amdgcn_mfma_f32_16x16x32_bf16(a[m], b[2], acc[m][2], 0, 0, 0);
            acc[m][3] = __builtin_amdgcn_mfma_f32_16x16x32_bf16(a[m], b[3], acc[m][3], 0, 0, 0);
        }
        __builtin_amdgcn_s_setprio(0);
        __builtin_amdgcn_sched_barrier(0);
    }
#undef STAGEH

    if (EPI == 3) {
        bf16* outp = (split < 2)
            ? (bf16*)Cout + (size_t)split * M * Nm
            : (bf16*)Cout2 + (size_t)(split - 2) * M * Nm;
#pragma unroll
        for (int n = 0; n < 4; ++n) {
            const int col = n0 + wn * 64 + n * 16 + lr;
#pragma unroll
            for (int m = 0; m < 8; ++m) {
                const int row = m0 + wm * 128 + m * 16 + lg * 4;
#pragma unroll
                for (int j = 0; j < 4; ++j)
                    outp[(size_t)(row + j) * Nm + col] = __float2bfloat16(acc[m][n][j]);
            }
        }
    } else if (EPI == 4 && n0 >= 2048) {
        // V tile: write transposed into vtg[(b*1024 + (col-2048))][n], N=2048
#pragma unroll
        for (int n = 0; n < 4; ++n) {
            const int col = n0 + wn * 64 + n * 16 + lr;
            const float bc = bias[col];
            const int vcol = col - 2048;
#pragma unroll
            for (int m = 0; m < 8; ++m) {
                const int row = m0 + wm * 128 + m * 16 + lg * 4;
                const int b = row >> 11, nn = row & 2047;
                ushort4 o = { f2b(acc[m][n][0] + bc), f2b(acc[m][n][1] + bc),
                              f2b(acc[m][n][2] + bc), f2b(acc[m][n][3] + bc) };
                *reinterpret_cast<ushort4*>(
                    (bf16*)Cout2 + ((size_t)(b * 1024 + vcol)) * 2048 + nn) = o;
            }
        }
    } else {
#pragma unroll
        for (int n = 0; n < 4; ++n) {
            const int col = n0 + wn * 64 + n * 16 + lr;
            const float bc = bias[col];
#pragma unroll
            for (int m = 0; m < 8; ++m) {
                const int row = m0 + wm * 128 + m * 16 + lg * 4;
#pragma unroll
                for (int j = 0; j < 4; ++j) {
                    float v = acc[m][n][j] + bc;
                    if (EPI == 1) v = gelu_fast(v);
                    reinterpret_cast<bf16*>(Cout)[(size_t)(row + j) * Nm + col] = __float2bfloat16(v);
                }
            }
        }
    }
}

// ---- flash attention, swapped-operand, QBLK=128, fixed-shift softmax -------
__global__ __launch_bounds__(256) void attn_fwd(const bf16* __restrict__ qkv,
                                                const bf16* __restrict__ vtg,
                                                bf16* __restrict__ o, int N) {
    __shared__ bf16 Ks[2][64][72];   // K tiles [kv][dh], padded
    __shared__ bf16 Vs[2][64][72];   // V^T tiles [dh][kv], padded
    __shared__ bf16 Ps[4][32][72];   // per-wave P [q][kv], padded
    const int nwg = gridDim.x, nbx = N / 128;
    int id = blockIdx.x;
    id = (id & 7) * (nwg >> 3) + (id >> 3);  // XCD-chunked
    const int bh = id / nbx, b = bh >> 4, h = bh & 15;
    const int q0 = (id % nbx) * 128;
    const int t = threadIdx.x, w = t >> 6, lane = t & 63;
    const int lr = lane & 15, lg = lane >> 4;
    const bf16* base = qkv + (size_t)b * N * 3072;
    const bf16* vbase = vtg + (size_t)bh * 64 * N;

    bf16x8 qf[2][2];
#pragma unroll
    for (int rb = 0; rb < 2; ++rb) {
        const bf16* qp = base + (size_t)(q0 + w * 32 + rb * 16 + lr) * 3072 + h * 64 + lg * 8;
        qf[rb][0] = *reinterpret_cast<const bf16x8*>(qp);
        qf[rb][1] = *reinterpret_cast<const bf16x8*>(qp + 32);
    }

    float lrow[2] = { 0.f, 0.f };
    f32x4 oacc[2][4] = {};
    const float scale2 = 0.03125f * 1.44269504088896340736f;  // embedDim^-0.5 * log2(e)
    const float MSHIFT = 16.0f;  // fixed softmax shift (exp2 domain); cancels in 1/lrow
    const int srow = t >> 2, scolb = (t & 3) * 8;

    const bf16* kptr = base + (size_t)srow * 3072 + 1024 + h * 64 + scolb;
    const bf16* vptr = vbase + (size_t)srow * N + scolb;

    uint4 k0 = *reinterpret_cast<const uint4*>(kptr);
    uint4 k1 = *reinterpret_cast<const uint4*>(kptr + 32);
    uint4 v0 = *reinterpret_cast<const uint4*>(vptr);
    uint4 v1 = *reinterpret_cast<const uint4*>(vptr + 32);
    *reinterpret_cast<uint4*>(&Ks[0][srow][scolb])      = k0;
    *reinterpret_cast<uint4*>(&Ks[0][srow][scolb + 32]) = k1;
    *reinterpret_cast<uint4*>(&Vs[0][srow][scolb])      = v0;
    *reinterpret_cast<uint4*>(&Vs[0][srow][scolb + 32]) = v1;

    int cur = 0;
    for (int kv0 = 0; kv0 < N; kv0 += 64) {
        __syncthreads();
        const bool more = (kv0 + 64) < N;
        if (more) {
            const bf16* kn = kptr + (size_t)(kv0 + 64) * 3072;
            const bf16* vn = vptr + (kv0 + 64);
            k0 = *reinterpret_cast<const uint4*>(kn);
            k1 = *reinterpret_cast<const uint4*>(kn + 32);
            v0 = *reinterpret_cast<const uint4*>(vn);
            v1 = *reinterpret_cast<const uint4*>(vn + 32);
        }
        __builtin_amdgcn_sched_barrier(0);

        f32x4 st[2][4] = {};
#pragma unroll
        for (int f = 0; f < 2; ++f)
#pragma unroll
            for (int c = 0; c < 4; ++c) {
                bf16x8 ka = *reinterpret_cast<const bf16x8*>(&Ks[cur][c * 16 + lr][f * 32 + lg * 8]);
                st[0][c] = __builtin_amdgcn_mfma_f32_16x16x32_bf16(ka, qf[0][f], st[0][c], 0, 0, 0);
                st[1][c] = __builtin_amdgcn_mfma_f32_16x16x32_bf16(ka, qf[1][f], st[1][c], 0, 0, 0);
            }

        // fixed-shift softmax: P = exp2(s*scale2 - MSHIFT); shift cancels in 1/lrow
#pragma unroll
        for (int rb = 0; rb < 2; ++rb) {
            float p[4][4];
            float psum = 0.f;
#pragma unroll
            for (int c = 0; c < 4; ++c)
#pragma unroll
                for (int j = 0; j < 4; ++j) {
                    p[c][j] = __builtin_amdgcn_exp2f(fmaf(st[rb][c][j], scale2, -MSHIFT));
                    psum += p[c][j];
                }
            psum += __shfl_xor(psum, 16, 64);
            psum += __shfl_xor(psum, 32, 64);
            lrow[rb] += psum;
#pragma unroll
            for (int c = 0; c < 4; ++c) {
                uint2 pr = { pack_bf16_trunc(p[c][0], p[c][1]),
                             pack_bf16_trunc(p[c][2], p[c][3]) };
                *reinterpret_cast<uint2*>(&Ps[w][rb * 16 + lr][c * 16 + lg * 4]) = pr;
            }
        }
        asm volatile("s_waitcnt lgkmcnt(0)" ::: "memory");
        __builtin_amdgcn_sched_barrier(0);

#pragma unroll
        for (int f = 0; f < 2; ++f) {
            bf16x8 pb0 = *reinterpret_cast<const bf16x8*>(&Ps[w][lr][f * 32 + lg * 8]);
            bf16x8 pb1 = *reinterpret_cast<const bf16x8*>(&Ps[w][16 + lr][f * 32 + lg * 8]);
#pragma unroll
            for (int c = 0; c < 4; ++c) {
                bf16x8 va = *reinterpret_cast<const bf16x8*>(&Vs[cur][c * 16 + lr][f * 32 + lg * 8]);
                oacc[0][c] = __builtin_amdgcn_mfma_f32_16x16x32_bf16(va, pb0, oacc[0][c], 0, 0, 0);
                oacc[1][c] = __builtin_amdgcn_mfma_f32_16x16x32_bf16(va, pb1, oacc[1][c], 0, 0, 0);
            }
        }

        if (more) {
            asm volatile("s_waitcnt vmcnt(0)" ::: "memory");
            __builtin_amdgcn_sched_barrier(0);
            *reinterpret_cast<uint4*>(&Ks[cur ^ 1][srow][scolb])      = k0;
            *reinterpret_cast<uint4*>(&Ks[cur ^ 1][srow][scolb + 32]) = k1;
            *reinterpret_cast<uint4*>(&Vs[cur ^ 1][srow][scolb])      = v0;
            *reinterpret_cast<uint4*>(&Vs[cur ^ 1][srow][scolb + 32]) = v1;
        }
        cur ^= 1;
    }

    // O^T layout: col q = lr, row d = 16c + 4lg + j -> ushort4 stores (bf16)
#pragma unroll
    for (int rb = 0; rb < 2; ++rb) {
        const float linv = 1.f / lrow[rb];
        bf16* op = o + ((size_t)b * N + q0 + w * 32 + rb * 16 + lr) * 1024 + h * 64;
#pragma unroll
        for (int c = 0; c < 4; ++c) {
            ushort4 v = { f2b(oacc[rb][c][0] * linv), f2b(oacc[rb][c][1] * linv),
                          f2b(oacc[rb][c][2] * linv), f2b(oacc[rb][c][3] * linv) };
            *reinterpret_cast<ushort4*>(op + c * 16 + lg * 4) = v;
        }
    }
}

// ---- LN1: h = LN(o + x), o bf16, x bf16 (or fp32 layer 0); writes hb bf16 --
__global__ __launch_bounds__(256) void ln_res(const bf16* __restrict__ a,
                                              const float* __restrict__ r32,
                                              const bf16* __restrict__ r16,
                                              const float* __restrict__ g,
                                              const float* __restrict__ be,
                                              bf16* __restrict__ yb) {
    const int row = blockIdx.x, t = threadIdx.x;
    ushort4 va = reinterpret_cast<const ushort4*>(a + (size_t)row * 1024)[t];
    float v0 = b2f(va.x), v1 = b2f(va.y), v2 = b2f(va.z), v3 = b2f(va.w);
    if (r32) {
        float4 vr = reinterpret_cast<const float4*>(r32 + (size_t)row * 1024)[t];
        v0 += vr.x; v1 += vr.y; v2 += vr.z; v3 += vr.w;
    } else {
        ushort4 vr = reinterpret_cast<const ushort4*>(r16 + (size_t)row * 1024)[t];
        v0 += b2f(vr.x); v1 += b2f(vr.y); v2 += b2f(vr.z); v3 += b2f(vr.w);
    }
    float s1 = v0 + v1 + v2 + v3;
    float s2 = v0 * v0 + v1 * v1 + v2 * v2 + v3 * v3;
#pragma unroll
    for (int m = 1; m < 64; m <<= 1) {
        s1 += __shfl_xor(s1, m, 64);
        s2 += __shfl_xor(s2, m, 64);
    }
    __shared__ float ws1[4], ws2[4];
    if ((t & 63) == 0) { ws1[t >> 6] = s1; ws2[t >> 6] = s2; }
    __syncthreads();
    s1 = ws1[0] + ws1[1] + ws1[2] + ws1[3];
    s2 = ws2[0] + ws2[1] + ws2[2] + ws2[3];
    const float mean = s1 * (1.f / 1024.f);
    const float var = s2 * (1.f / 1024.f) - mean * mean;
    const float rstd = rsqrtf(var + 1e-5f);
    float4 gg = reinterpret_cast<const float4*>(g)[t];
    float4 bb = reinterpret_cast<const float4*>(be)[t];
    float o0 = (v0 - mean) * rstd * gg.x + bb.x;
    float o1 = (v1 - mean) * rstd * gg.y + bb.y;
    float o2 = (v2 - mean) * rstd * gg.z + bb.z;
    float o3 = (v3 - mean) * rstd * gg.w + bb.w;
    ushort4 ob = { f2b(o0), f2b(o1), f2b(o2), f2b(o3) };
    reinterpret_cast<ushort4*>(yb + (size_t)row * 1024)[t] = ob;
}

// ---- LN2: f2 = gelu(sum 4 bf16 partials + b2); x = LN(f2 + h), h bf16 ------
__global__ __launch_bounds__(256) void ln_res_red4(const bf16* __restrict__ p0,
                                                   const bf16* __restrict__ p2,
                                                   const float* __restrict__ bias,
                                                   const bf16* __restrict__ r,
                                                   const float* __restrict__ g,
                                                   const float* __restrict__ be,
                                                   float* __restrict__ y,
                                                   bf16* __restrict__ yb,
                                                   size_t stride) {
    const int row = blockIdx.x, t = threadIdx.x;
    const size_t off = (size_t)row * 1024 + t * 4;
    float4 bb4 = reinterpret_cast<const float4*>(bias)[t];
    float s0 = bb4.x, s1v = bb4.y, s2v = bb4.z, s3 = bb4.w;
#pragma unroll
    for (int k = 0; k < 2; ++k) {
        ushort4 va = *reinterpret_cast<const ushort4*>(p0 + k * stride + off);
        s0 += b2f(va.x); s1v += b2f(va.y); s2v += b2f(va.z); s3 += b2f(va.w);
        ushort4 vb = *reinterpret_cast<const ushort4*>(p2 + k * stride + off);
        s0 += b2f(vb.x); s1v += b2f(vb.y); s2v += b2f(vb.z); s3 += b2f(vb.w);
    }
    ushort4 vr = *reinterpret_cast<const ushort4*>(r + off);
    float v0 = gelu_fast(s0) + b2f(vr.x);
    float v1 = gelu_fast(s1v) + b2f(vr.y);
    float v2 = gelu_fast(s2v) + b2f(vr.z);
    float v3 = gelu_fast(s3) + b2f(vr.w);
    float s1 = v0 + v1 + v2 + v3;
    float s2 = v0 * v0 + v1 * v1 + v2 * v2 + v3 * v3;
#pragma unroll
    for (int m = 1; m < 64; m <<= 1) {
        s1 += __shfl_xor(s1, m, 64);
        s2 += __shfl_xor(s2, m, 64);
    }
    __shared__ float ws1[4], ws2[4];
    if ((t & 63) == 0) { ws1[t >> 6] = s1; ws2[t >> 6] = s2; }
    __syncthreads();
    s1 = ws1[0] + ws1[1] + ws1[2] + ws1[3];
    s2 = ws2[0] + ws2[1] + ws2[2] + ws2[3];
    const float mean = s1 * (1.f / 1024.f);
    const float var = s2 * (1.f / 1024.f) - mean * mean;
    const float rstd = rsqrtf(var + 1e-5f);
    float4 gg = reinterpret_cast<const float4*>(g)[t];
    float4 bb = reinterpret_cast<const float4*>(be)[t];
    float o0 = (v0 - mean) * rstd * gg.x + bb.x;
    float o1 = (v1 - mean) * rstd * gg.y + bb.y;
    float o2 = (v2 - mean) * rstd * gg.z + bb.z;
    float o3 = (v3 - mean) * rstd * gg.w + bb.w;
    if (y) {
        float4 out = { o0, o1, o2, o3 };
        reinterpret_cast<float4*>(y + (size_t)row * 1024)[t] = out;
    }
    ushort4 ob = { f2b(o0), f2b(o1), f2b(o2), f2b(o3) };
    reinterpret_cast<ushort4*>(yb + (size_t)row * 1024)[t] = ob;
}

// ---------------------------------------------------------------------------
extern "C" void kernel_launch(void* const* d_in, const int* in_sizes, int n_in,
                              void* d_out, int out_size, void* d_ws, size_t ws_size,
                              hipStream_t stream) {
    const float* x_in = (const float*)d_in[0];
    const float* Wqkv = (const float*)d_in[1];
    const float* bqkv = (const float*)d_in[2];
    const float* W1   = (const float*)d_in[3];
    const float* b1   = (const float*)d_in[4];
    const float* W2   = (const float*)d_in[5];
    const float* b2   = (const float*)d_in[6];
    const float* g1   = (const float*)d_in[7];
    const float* be1  = (const float*)d_in[8];
    const float* g2   = (const float*)d_in[9];
    const float* be2  = (const float*)d_in[10];

    const int Bv = 2, N = 2048, L = 4, Hh = 16;
    const int R = Bv * N;  // 4096 token rows

    char* p = (char*)d_ws;
    auto alloc = [&](size_t bytes) { char* r = p; p += (bytes + 255) & ~(size_t)255; return r; };
    bf16*  Wqkvt = (bf16*)alloc((size_t)L * 3072 * 1024 * 2);
    bf16*  W1t   = (bf16*)alloc((size_t)L * 4096 * 1024 * 2);
    bf16*  W2t   = (bf16*)alloc((size_t)L * 1024 * 4096 * 2);
    bf16*  xb    = (bf16*)alloc((size_t)R * 1024 * 2);
    bf16*  qkvb  = (bf16*)alloc((size_t)R * 3072 * 2);
    float* obuf  = (float*)alloc((size_t)R * 1024 * 4);   // region: attn bf16 out + part0
    float* hbuf  = (float*)alloc((size_t)R * 1024 * 4);   // region: vtg
    bf16*  hb    = (bf16*)alloc((size_t)R * 1024 * 2);
    bf16*  f1b   = (bf16*)alloc((size_t)R * 4096 * 2);
    bf16*  vtg   = (bf16*)hbuf;   // 8.4MB V^T
    bf16*  ob    = (bf16*)obuf;   // attn bf16 output
    bf16*  part0 = (bf16*)obuf;   // split-K partials 0,1 (dead after LN1)
    bf16*  part2 = (bf16*)qkvb;   // split-K partials 2,3 (dead after attn)

    transpose_cast<<<dim3(3072 / 64, 1024 / 32, L), 256, 0, stream>>>(Wqkv, Wqkvt, 1024, 3072);
    transpose_cast<<<dim3(4096 / 64, 1024 / 32, L), 256, 0, stream>>>(W1, W1t, 1024, 4096);
    transpose_cast<<<dim3(1024 / 64, 4096 / 32, L), 256, 0, stream>>>(W2, W2t, 4096, 1024);
    cast_bf16_k<<<(R * 1024 / 4 + 255) / 256, 256, 0, stream>>>(x_in, xb, R * 1024 / 4);

    for (int l = 0; l < L; ++l) {
        // qkv = x @ Wqkv + bqkv; Q/K -> qkvb, V -> transposed vtg (4-phase EPI4)
        gemm256p<4><<<(R / 256) * (3072 / 256), 512, 0, stream>>>(
            xb, Wqkvt + (size_t)l * 3072 * 1024, bqkv + l * 3072, qkvb, vtg,
            R, 3072, 1024, 3072 / 256, (R / 256) * (3072 / 256), 1024);
        // o = softmax(q k^T / 32) v -> bf16   (QBLK=128, 512 blocks)
        attn_fwd<<<(N / 128) * (Bv * Hh), 256, 0, stream>>>(qkvb, vtg, ob, N);
        // h = LN(o + x) -> hb bf16  (residual: fp32 x_in layer 0, else bf16 xb)
        ln_res<<<R, 256, 0, stream>>>(ob, l == 0 ? x_in : nullptr,
                                      l == 0 ? nullptr : xb,
                                      g1 + l * 1024, be1 + l * 1024, hb);
        // f1 = gelu(h @ W1 + b1) -> bf16  (4-phase pipelined + swizzle)
        gemm256p<1><<<(R / 256) * (4096 / 256), 512, 0, stream>>>(
            hb, W1t + (size_t)l * 4096 * 1024, b1 + l * 4096, f1b, nullptr,
            R, 4096, 1024, 4096 / 256, (R / 256) * (4096 / 256), 1024);
        // f2 partials: f1 @ W2 split-K=4 -> bf16 into part0 (s0,s1) / part2 (s2,s3)
        gemm256p<3><<<(R / 256) * (1024 / 256) * 4, 512, 0, stream>>>(
            f1b, W2t + (size_t)l * 1024 * 4096, nullptr, part0, part2,
            R, 1024, 1024, 1024 / 256, (R / 256) * (1024 / 256), 4096);
        // x = LN(gelu(sum partials + b2) + h) -> xb bf16 (+ fp32 d_out last layer)
        ln_res_red4<<<R, 256, 0, stream>>>(part0, part2, b2 + l * 1024, hb,
                                           g2 + l * 1024, be2 + l * 1024,
                                           l == L - 1 ? (float*)d_out : nullptr,
                                           xb, (size_t)R * 1024);
    }
}

// Round 22
// 948.976 us; speedup vs baseline: 1.0254x; 1.0214x over previous
//
#include <hip/hip_runtime.h>
#include <hip/hip_bf16.h>
#include <cmath>

// ---------------------------------------------------------------------------
// TextEncoder: 4-layer post-LN transformer, B=2 N=2048 D=1024 H=16 dh=64 FF=4096
// R21: attn row-sum moved to the MFMA pipe: lrow = (ones-row . P) accumulated
// by 4 extra MFMAs/tile (A = all-ones fragment; every output row = column sum,
// so no cross-lane reduce at all). Deletes 32 VALU adds + 4 shuffles per tile
// from the 36%-busy VALU pipe. Rest unchanged from R18.
// ---------------------------------------------------------------------------

typedef __attribute__((ext_vector_type(8))) short bf16x8;
typedef __attribute__((ext_vector_type(4))) float f32x4;
typedef __hip_bfloat16 bf16;

#define DEV static __device__ __forceinline__

DEV unsigned short f2b(float f) {
    bf16 h = __float2bfloat16(f);
    return *reinterpret_cast<unsigned short*>(&h);
}

// truncation pack: two non-negative floats -> packed bf16 pair (lo | hi<<16)
DEV unsigned int pack_bf16_trunc(float lo, float hi) {
    unsigned int ulo = *reinterpret_cast<unsigned int*>(&lo);
    unsigned int uhi = *reinterpret_cast<unsigned int*>(&hi);
    return (uhi & 0xFFFF0000u) | (ulo >> 16);
}

DEV float b2f(unsigned short u) {
    unsigned int x = ((unsigned int)u) << 16;
    return *reinterpret_cast<float*>(&x);
}

// tanh-form gelu: max abs deviation from exact ~1e-3, ~10 VALU ops.
DEV float gelu_fast(float x) {
    float u = 0.7978845608028654f * fmaf(0.044715f * x, x * x, x);
    u = fminf(fmaxf(u, -15.f), 15.f);
    float t = __builtin_amdgcn_exp2f(u * 2.8853900817779268f);
    float th = (t - 1.0f) * __builtin_amdgcn_rcpf(t + 1.0f);
    return 0.5f * x * (1.0f + th);
}

DEV void gload_lds16(const bf16* g, bf16* l) {
    __builtin_amdgcn_global_load_lds(
        (const __attribute__((address_space(1))) void*)g,
        (__attribute__((address_space(3))) void*)l, 16, 0, 0);
}

// ---- weight transpose + cast: Wt[l][n][k] = (bf16) W[l][k][n] --------------
// 64(n) x 32(k) tiles; coalesced fp32 reads, one 16B bf16x8 store per thread.
__global__ __launch_bounds__(256) void transpose_cast(const float* __restrict__ W,
                                                      bf16* __restrict__ Wt,
                                                      int K, int Nm) {
    __shared__ float tile[64][33];
    const int l = blockIdx.z;
    const float* Wl = W + (size_t)l * K * Nm;
    bf16* Wtl = Wt + (size_t)l * K * Nm;
    const int n0 = blockIdx.x * 64, k0 = blockIdx.y * 32;
    const int t = threadIdx.x;
    const int tx = t & 63, ty = t >> 6;      // read: n = n0+tx, k = k0+ty+4i
#pragma unroll
    for (int i = 0; i < 8; ++i)
        tile[tx][ty + 4 * i] = Wl[(size_t)(k0 + ty + 4 * i) * Nm + n0 + tx];
    __syncthreads();
    const int nr = t >> 2, kq = (t & 3) * 8; // write: row n0+nr, 8 bf16 at k0+kq
    union { unsigned short s[8]; uint4 v; } o;
#pragma unroll
    for (int e = 0; e < 8; ++e)
        o.s[e] = f2b(tile[nr][kq + e]);
    *reinterpret_cast<uint4*>(&Wtl[(size_t)(n0 + nr) * K + k0 + kq]) = o.v;
}

// ---- elementwise fp32 -> bf16 ----------------------------------------------
__global__ __launch_bounds__(256) void cast_bf16_k(const float* __restrict__ in,
                                                   bf16* __restrict__ out, int n4) {
    int i = blockIdx.x * 256 + threadIdx.x;
    if (i >= n4) return;
    float4 v = reinterpret_cast<const float4*>(in)[i];
    ushort4 o = { f2b(v.x), f2b(v.y), f2b(v.z), f2b(v.w) };
    reinterpret_cast<ushort4*>(out)[i] = o;
}

// ---- 256x256 4-phase-per-K-tile GEMM with T2 swizzle ------------------------
// EPI: 1 = bias+gelu -> bf16 out; 3 = raw bf16 partials to Cout (splits 0,1)
// / Cout2 (splits 2,3); 4 = qkv: Q/K cols -> bias bf16 Cout, V cols
// (n0 >= 2048) -> bias + TRANSPOSED ushort4 into Cout2 (vtg layout, N=2048).
template <int EPI>
__global__ __launch_bounds__(512, 2) void gemm256p(const bf16* __restrict__ A,
                                                   const bf16* __restrict__ Bt,
                                                   const float* __restrict__ bias,
                                                   void* __restrict__ Cout,
                                                   void* __restrict__ Cout2,
                                                   int M, int Nm, int K,
                                                   int nbx, int ntiles, int Ktotal) {
    __shared__ bf16 As[2][256][64];   // 64 KB
    __shared__ bf16 Bs[2][256][64];   // 64 KB
    const int nwg = gridDim.x;
    int id = blockIdx.x;
    id = (id & 7) * (nwg >> 3) + (id >> 3);          // bijective: nwg % 8 == 0
    const int tile = id % ntiles, split = id / ntiles;
    const int m0 = (tile / nbx) * 256, n0 = (tile % nbx) * 256;
    const int kbase = split * K;
    const int t = threadIdx.x, lane = t & 63;
    const int w = t >> 6;
    const int wm = w >> 2, wn = w & 3;               // 2 x 4 wave grid
    const int lr = lane & 15, lg = lane >> 4;
    const int srowt = t >> 3;                        // staging row 0..63
    const int scol = (t & 7) * 8;                    // linear LDS chunk col
    const int gcol = (((t & 7) ^ ((t >> 3) & 7)) * 8);  // swizzled global col
    const bf16* Ag = A + (size_t)(m0 + srowt) * Ktotal + kbase + gcol;
    const bf16* Bg = Bt + (size_t)(n0 + srowt) * Ktotal + kbase + gcol;
    const int cidx0 = ((lg) ^ (lr & 7)) * 8;         // kk=0 read chunk
    const int cidx1 = ((4 + lg) ^ (lr & 7)) * 8;     // kk=1 read chunk

    f32x4 acc[8][4] = {};
    const int NT = K / 64;

#define STAGEH(h, kt, d)                                                         \
    {                                                                            \
        const size_t koff = (size_t)(kt) * 64;                                   \
        _Pragma("unroll")                                                        \
        for (int p = 0; p < 2; ++p) {                                            \
            const int roff = ((h) & 1) * 128 + p * 64;                           \
            if ((h) < 2)                                                         \
                gload_lds16(Ag + (size_t)roff * Ktotal + koff,                   \
                            &As[d][roff + srowt][scol]);                         \
            else                                                                 \
                gload_lds16(Bg + (size_t)roff * Ktotal + koff,                   \
                            &Bs[d][roff + srowt][scol]);                         \
        }                                                                        \
    }

    STAGEH(0, 0, 0); STAGEH(1, 0, 0); STAGEH(2, 0, 0); STAGEH(3, 0, 0);

    for (int kt = 0; kt < NT; ++kt) {
        const int d = kt & 1;
        const bool more = (kt + 1) < NT;
        asm volatile("s_waitcnt vmcnt(0)" ::: "memory");
        __builtin_amdgcn_sched_barrier(0);
        __builtin_amdgcn_s_barrier();
        __builtin_amdgcn_sched_barrier(0);

        bf16x8 a[8], b[4];

        // ---- phase 0: kk=0, n={0,1} ----
        if (more) STAGEH(0, kt + 1, d ^ 1);
#pragma unroll
        for (int m = 0; m < 8; ++m)
            a[m] = *reinterpret_cast<const bf16x8*>(&As[d][wm * 128 + m * 16 + lr][cidx0]);
        b[0] = *reinterpret_cast<const bf16x8*>(&Bs[d][wn * 64 + lr][cidx0]);
        b[1] = *reinterpret_cast<const bf16x8*>(&Bs[d][wn * 64 + 16 + lr][cidx0]);
        __builtin_amdgcn_sched_barrier(0);
        __builtin_amdgcn_s_barrier();
        asm volatile("s_waitcnt lgkmcnt(0)" ::: "memory");
        __builtin_amdgcn_sched_barrier(0);
        __builtin_amdgcn_s_setprio(1);
#pragma unroll
        for (int m = 0; m < 8; ++m) {
            acc[m][0] = __builtin_amdgcn_mfma_f32_16x16x32_bf16(a[m], b[0], acc[m][0], 0, 0, 0);
            acc[m][1] = __builtin_amdgcn_mfma_f32_16x16x32_bf16(a[m], b[1], acc[m][1], 0, 0, 0);
        }
        __builtin_amdgcn_s_setprio(0);
        __builtin_amdgcn_sched_barrier(0);

        // ---- phase 1: kk=0, n={2,3} ----
        if (more) STAGEH(1, kt + 1, d ^ 1);
        b[2] = *reinterpret_cast<const bf16x8*>(&Bs[d][wn * 64 + 32 + lr][cidx0]);
        b[3] = *reinterpret_cast<const bf16x8*>(&Bs[d][wn * 64 + 48 + lr][cidx0]);
        __builtin_amdgcn_sched_barrier(0);
        __builtin_amdgcn_s_barrier();
        asm volatile("s_waitcnt lgkmcnt(0)" ::: "memory");
        __builtin_amdgcn_sched_barrier(0);
        __builtin_amdgcn_s_setprio(1);
#pragma unroll
        for (int m = 0; m < 8; ++m) {
            acc[m][2] = __builtin_amdgcn_mfma_f32_16x16x32_bf16(a[m], b[2], acc[m][2], 0, 0, 0);
            acc[m][3] = __builtin_amdgcn_mfma_f32_16x16x32_bf16(a[m], b[3], acc[m][3], 0, 0, 0);
        }
        __builtin_amdgcn_s_setprio(0);
        __builtin_amdgcn_sched_barrier(0);

        // ---- phase 2: kk=1, n={0,1} ----
        if (more) STAGEH(2, kt + 1, d ^ 1);
#pragma unroll
        for (int m = 0; m < 8; ++m)
            a[m] = *reinterpret_cast<const bf16x8*>(&As[d][wm * 128 + m * 16 + lr][cidx1]);
        b[0] = *reinterpret_cast<const bf16x8*>(&Bs[d][wn * 64 + lr][cidx1]);
        b[1] = *reinterpret_cast<const bf16x8*>(&Bs[d][wn * 64 + 16 + lr][cidx1]);
        __builtin_amdgcn_sched_barrier(0);
        __builtin_amdgcn_s_barrier();
        asm volatile("s_waitcnt lgkmcnt(0)" ::: "memory");
        __builtin_amdgcn_sched_barrier(0);
        __builtin_amdgcn_s_setprio(1);
#pragma unroll
        for (int m = 0; m < 8; ++m) {
            acc[m][0] = __builtin_amdgcn_mfma_f32_16x16x32_bf16(a[m], b[0], acc[m][0], 0, 0, 0);
            acc[m][1] = __builtin_amdgcn_mfma_f32_16x16x32_bf16(a[m], b[1], acc[m][1], 0, 0, 0);
        }
        __builtin_amdgcn_s_setprio(0);
        __builtin_amdgcn_sched_barrier(0);

        // ---- phase 3: kk=1, n={2,3} ----
        if (more) STAGEH(3, kt + 1, d ^ 1);
        b[2] = *reinterpret_cast<const bf16x8*>(&Bs[d][wn * 64 + 32 + lr][cidx1]);
        b[3] = *reinterpret_cast<const bf16x8*>(&Bs[d][wn * 64 + 48 + lr][cidx1]);
        __builtin_amdgcn_sched_barrier(0);
        __builtin_amdgcn_s_barrier();
        asm volatile("s_waitcnt lgkmcnt(0)" ::: "memory");
        __builtin_amdgcn_sched_barrier(0);
        __builtin_amdgcn_s_setprio(1);
#pragma unroll
        for (int m = 0; m < 8; ++m) {
            acc[m][2] = __builtin_amdgcn_mfma_f32_16x16x32_bf16(a[m], b[2], acc[m][2], 0, 0, 0);
            acc[m][3] = __builtin_amdgcn_mfma_f32_16x16x32_bf16(a[m], b[3], acc[m][3], 0, 0, 0);
        }
        __builtin_amdgcn_s_setprio(0);
        __builtin_amdgcn_sched_barrier(0);
    }
#undef STAGEH

    if (EPI == 3) {
        bf16* outp = (split < 2)
            ? (bf16*)Cout + (size_t)split * M * Nm
            : (bf16*)Cout2 + (size_t)(split - 2) * M * Nm;
#pragma unroll
        for (int n = 0; n < 4; ++n) {
            const int col = n0 + wn * 64 + n * 16 + lr;
#pragma unroll
            for (int m = 0; m < 8; ++m) {
                const int row = m0 + wm * 128 + m * 16 + lg * 4;
#pragma unroll
                for (int j = 0; j < 4; ++j)
                    outp[(size_t)(row + j) * Nm + col] = __float2bfloat16(acc[m][n][j]);
            }
        }
    } else if (EPI == 4 && n0 >= 2048) {
        // V tile: write transposed into vtg[(b*1024 + (col-2048))][n], N=2048
#pragma unroll
        for (int n = 0; n < 4; ++n) {
            const int col = n0 + wn * 64 + n * 16 + lr;
            const float bc = bias[col];
            const int vcol = col - 2048;
#pragma unroll
            for (int m = 0; m < 8; ++m) {
                const int row = m0 + wm * 128 + m * 16 + lg * 4;
                const int b = row >> 11, nn = row & 2047;
                ushort4 o = { f2b(acc[m][n][0] + bc), f2b(acc[m][n][1] + bc),
                              f2b(acc[m][n][2] + bc), f2b(acc[m][n][3] + bc) };
                *reinterpret_cast<ushort4*>(
                    (bf16*)Cout2 + ((size_t)(b * 1024 + vcol)) * 2048 + nn) = o;
            }
        }
    } else {
#pragma unroll
        for (int n = 0; n < 4; ++n) {
            const int col = n0 + wn * 64 + n * 16 + lr;
            const float bc = bias[col];
#pragma unroll
            for (int m = 0; m < 8; ++m) {
                const int row = m0 + wm * 128 + m * 16 + lg * 4;
#pragma unroll
                for (int j = 0; j < 4; ++j) {
                    float v = acc[m][n][j] + bc;
                    if (EPI == 1) v = gelu_fast(v);
                    reinterpret_cast<bf16*>(Cout)[(size_t)(row + j) * Nm + col] = __float2bfloat16(v);
                }
            }
        }
    }
}

// ---- flash attention, swapped-operand, QBLK=128, fixed-shift softmax -------
// Row-sum via ones-MFMA: lrow[rb] accumulated on the matrix pipe.
__global__ __launch_bounds__(256) void attn_fwd(const bf16* __restrict__ qkv,
                                                const bf16* __restrict__ vtg,
                                                bf16* __restrict__ o, int N) {
    __shared__ bf16 Ks[2][64][72];   // K tiles [kv][dh], padded
    __shared__ bf16 Vs[2][64][72];   // V^T tiles [dh][kv], padded
    __shared__ bf16 Ps[4][32][72];   // per-wave P [q][kv], padded
    const int nwg = gridDim.x, nbx = N / 128;
    int id = blockIdx.x;
    id = (id & 7) * (nwg >> 3) + (id >> 3);  // XCD-chunked
    const int bh = id / nbx, b = bh >> 4, h = bh & 15;
    const int q0 = (id % nbx) * 128;
    const int t = threadIdx.x, w = t >> 6, lane = t & 63;
    const int lr = lane & 15, lg = lane >> 4;
    const bf16* base = qkv + (size_t)b * N * 3072;
    const bf16* vbase = vtg + (size_t)bh * 64 * N;

    bf16x8 qf[2][2];
#pragma unroll
    for (int rb = 0; rb < 2; ++rb) {
        const bf16* qp = base + (size_t)(q0 + w * 32 + rb * 16 + lr) * 3072 + h * 64 + lg * 8;
        qf[rb][0] = *reinterpret_cast<const bf16x8*>(qp);
        qf[rb][1] = *reinterpret_cast<const bf16x8*>(qp + 32);
    }

    // all-ones A fragment: every output row of mfma(ones, P) = column-sum of P
    union { unsigned short s[8]; bf16x8 v; } a1u;
#pragma unroll
    for (int e = 0; e < 8; ++e) a1u.s[e] = 0x3F80;  // bf16 1.0
    const bf16x8 a_ones = a1u.v;

    f32x4 osum[2] = {};              // row-sum accumulators (all lanes identical rows)
    f32x4 oacc[2][4] = {};
    const float scale2 = 0.03125f * 1.44269504088896340736f;  // embedDim^-0.5 * log2(e)
    const float MSHIFT = 16.0f;  // fixed softmax shift (exp2 domain); cancels in 1/sum
    const int srow = t >> 2, scolb = (t & 3) * 8;

    const bf16* kptr = base + (size_t)srow * 3072 + 1024 + h * 64 + scolb;
    const bf16* vptr = vbase + (size_t)srow * N + scolb;

    uint4 k0 = *reinterpret_cast<const uint4*>(kptr);
    uint4 k1 = *reinterpret_cast<const uint4*>(kptr + 32);
    uint4 v0 = *reinterpret_cast<const uint4*>(vptr);
    uint4 v1 = *reinterpret_cast<const uint4*>(vptr + 32);
    *reinterpret_cast<uint4*>(&Ks[0][srow][scolb])      = k0;
    *reinterpret_cast<uint4*>(&Ks[0][srow][scolb + 32]) = k1;
    *reinterpret_cast<uint4*>(&Vs[0][srow][scolb])      = v0;
    *reinterpret_cast<uint4*>(&Vs[0][srow][scolb + 32]) = v1;

    int cur = 0;
    for (int kv0 = 0; kv0 < N; kv0 += 64) {
        __syncthreads();
        const bool more = (kv0 + 64) < N;
        if (more) {
            const bf16* kn = kptr + (size_t)(kv0 + 64) * 3072;
            const bf16* vn = vptr + (kv0 + 64);
            k0 = *reinterpret_cast<const uint4*>(kn);
            k1 = *reinterpret_cast<const uint4*>(kn + 32);
            v0 = *reinterpret_cast<const uint4*>(vn);
            v1 = *reinterpret_cast<const uint4*>(vn + 32);
        }
        __builtin_amdgcn_sched_barrier(0);

        f32x4 st[2][4] = {};
#pragma unroll
        for (int f = 0; f < 2; ++f)
#pragma unroll
            for (int c = 0; c < 4; ++c) {
                bf16x8 ka = *reinterpret_cast<const bf16x8*>(&Ks[cur][c * 16 + lr][f * 32 + lg * 8]);
                st[0][c] = __builtin_amdgcn_mfma_f32_16x16x32_bf16(ka, qf[0][f], st[0][c], 0, 0, 0);
                st[1][c] = __builtin_amdgcn_mfma_f32_16x16x32_bf16(ka, qf[1][f], st[1][c], 0, 0, 0);
            }

        // fixed-shift softmax: P = exp2(s*scale2 - MSHIFT); no row-sum here
#pragma unroll
        for (int rb = 0; rb < 2; ++rb) {
            float p[4][4];
#pragma unroll
            for (int c = 0; c < 4; ++c)
#pragma unroll
                for (int j = 0; j < 4; ++j)
                    p[c][j] = __builtin_amdgcn_exp2f(fmaf(st[rb][c][j], scale2, -MSHIFT));
#pragma unroll
            for (int c = 0; c < 4; ++c) {
                uint2 pr = { pack_bf16_trunc(p[c][0], p[c][1]),
                             pack_bf16_trunc(p[c][2], p[c][3]) };
                *reinterpret_cast<uint2*>(&Ps[w][rb * 16 + lr][c * 16 + lg * 4]) = pr;
            }
        }
        asm volatile("s_waitcnt lgkmcnt(0)" ::: "memory");
        __builtin_amdgcn_sched_barrier(0);

#pragma unroll
        for (int f = 0; f < 2; ++f) {
            bf16x8 pb0 = *reinterpret_cast<const bf16x8*>(&Ps[w][lr][f * 32 + lg * 8]);
            bf16x8 pb1 = *reinterpret_cast<const bf16x8*>(&Ps[w][16 + lr][f * 32 + lg * 8]);
            osum[0] = __builtin_amdgcn_mfma_f32_16x16x32_bf16(a_ones, pb0, osum[0], 0, 0, 0);
            osum[1] = __builtin_amdgcn_mfma_f32_16x16x32_bf16(a_ones, pb1, osum[1], 0, 0, 0);
#pragma unroll
            for (int c = 0; c < 4; ++c) {
                bf16x8 va = *reinterpret_cast<const bf16x8*>(&Vs[cur][c * 16 + lr][f * 32 + lg * 8]);
                oacc[0][c] = __builtin_amdgcn_mfma_f32_16x16x32_bf16(va, pb0, oacc[0][c], 0, 0, 0);
                oacc[1][c] = __builtin_amdgcn_mfma_f32_16x16x32_bf16(va, pb1, oacc[1][c], 0, 0, 0);
            }
        }

        if (more) {
            asm volatile("s_waitcnt vmcnt(0)" ::: "memory");
            __builtin_amdgcn_sched_barrier(0);
            *reinterpret_cast<uint4*>(&Ks[cur ^ 1][srow][scolb])      = k0;
            *reinterpret_cast<uint4*>(&Ks[cur ^ 1][srow][scolb + 32]) = k1;
            *reinterpret_cast<uint4*>(&Vs[cur ^ 1][srow][scolb])      = v0;
            *reinterpret_cast<uint4*>(&Vs[cur ^ 1][srow][scolb + 32]) = v1;
        }
        cur ^= 1;
    }

    // O^T layout: col q = lr, row d = 16c + 4lg + j -> ushort4 stores (bf16)
#pragma unroll
    for (int rb = 0; rb < 2; ++rb) {
        const float linv = 1.f / osum[rb][0];   // all rows of osum identical
        bf16* op = o + ((size_t)b * N + q0 + w * 32 + rb * 16 + lr) * 1024 + h * 64;
#pragma unroll
        for (int c = 0; c < 4; ++c) {
            ushort4 v = { f2b(oacc[rb][c][0] * linv), f2b(oacc[rb][c][1] * linv),
                          f2b(oacc[rb][c][2] * linv), f2b(oacc[rb][c][3] * linv) };
            *reinterpret_cast<ushort4*>(op + c * 16 + lg * 4) = v;
        }
    }
}

// ---- LN1: h = LN(o + x), o bf16, x bf16 (or fp32 layer 0); writes hb bf16 --
__global__ __launch_bounds__(256) void ln_res(const bf16* __restrict__ a,
                                              const float* __restrict__ r32,
                                              const bf16* __restrict__ r16,
                                              const float* __restrict__ g,
                                              const float* __restrict__ be,
                                              bf16* __restrict__ yb) {
    const int row = blockIdx.x, t = threadIdx.x;
    ushort4 va = reinterpret_cast<const ushort4*>(a + (size_t)row * 1024)[t];
    float v0 = b2f(va.x), v1 = b2f(va.y), v2 = b2f(va.z), v3 = b2f(va.w);
    if (r32) {
        float4 vr = reinterpret_cast<const float4*>(r32 + (size_t)row * 1024)[t];
        v0 += vr.x; v1 += vr.y; v2 += vr.z; v3 += vr.w;
    } else {
        ushort4 vr = reinterpret_cast<const ushort4*>(r16 + (size_t)row * 1024)[t];
        v0 += b2f(vr.x); v1 += b2f(vr.y); v2 += b2f(vr.z); v3 += b2f(vr.w);
    }
    float s1 = v0 + v1 + v2 + v3;
    float s2 = v0 * v0 + v1 * v1 + v2 * v2 + v3 * v3;
#pragma unroll
    for (int m = 1; m < 64; m <<= 1) {
        s1 += __shfl_xor(s1, m, 64);
        s2 += __shfl_xor(s2, m, 64);
    }
    __shared__ float ws1[4], ws2[4];
    if ((t & 63) == 0) { ws1[t >> 6] = s1; ws2[t >> 6] = s2; }
    __syncthreads();
    s1 = ws1[0] + ws1[1] + ws1[2] + ws1[3];
    s2 = ws2[0] + ws2[1] + ws2[2] + ws2[3];
    const float mean = s1 * (1.f / 1024.f);
    const float var = s2 * (1.f / 1024.f) - mean * mean;
    const float rstd = rsqrtf(var + 1e-5f);
    float4 gg = reinterpret_cast<const float4*>(g)[t];
    float4 bb = reinterpret_cast<const float4*>(be)[t];
    float o0 = (v0 - mean) * rstd * gg.x + bb.x;
    float o1 = (v1 - mean) * rstd * gg.y + bb.y;
    float o2 = (v2 - mean) * rstd * gg.z + bb.z;
    float o3 = (v3 - mean) * rstd * gg.w + bb.w;
    ushort4 ob = { f2b(o0), f2b(o1), f2b(o2), f2b(o3) };
    reinterpret_cast<ushort4*>(yb + (size_t)row * 1024)[t] = ob;
}

// ---- LN2: f2 = gelu(sum 4 bf16 partials + b2); x = LN(f2 + h), h bf16 ------
__global__ __launch_bounds__(256) void ln_res_red4(const bf16* __restrict__ p0,
                                                   const bf16* __restrict__ p2,
                                                   const float* __restrict__ bias,
                                                   const bf16* __restrict__ r,
                                                   const float* __restrict__ g,
                                                   const float* __restrict__ be,
                                                   float* __restrict__ y,
                                                   bf16* __restrict__ yb,
                                                   size_t stride) {
    const int row = blockIdx.x, t = threadIdx.x;
    const size_t off = (size_t)row * 1024 + t * 4;
    float4 bb4 = reinterpret_cast<const float4*>(bias)[t];
    float s0 = bb4.x, s1v = bb4.y, s2v = bb4.z, s3 = bb4.w;
#pragma unroll
    for (int k = 0; k < 2; ++k) {
        ushort4 va = *reinterpret_cast<const ushort4*>(p0 + k * stride + off);
        s0 += b2f(va.x); s1v += b2f(va.y); s2v += b2f(va.z); s3 += b2f(va.w);
        ushort4 vb = *reinterpret_cast<const ushort4*>(p2 + k * stride + off);
        s0 += b2f(vb.x); s1v += b2f(vb.y); s2v += b2f(vb.z); s3 += b2f(vb.w);
    }
    ushort4 vr = *reinterpret_cast<const ushort4*>(r + off);
    float v0 = gelu_fast(s0) + b2f(vr.x);
    float v1 = gelu_fast(s1v) + b2f(vr.y);
    float v2 = gelu_fast(s2v) + b2f(vr.z);
    float v3 = gelu_fast(s3) + b2f(vr.w);
    float s1 = v0 + v1 + v2 + v3;
    float s2 = v0 * v0 + v1 * v1 + v2 * v2 + v3 * v3;
#pragma unroll
    for (int m = 1; m < 64; m <<= 1) {
        s1 += __shfl_xor(s1, m, 64);
        s2 += __shfl_xor(s2, m, 64);
    }
    __shared__ float ws1[4], ws2[4];
    if ((t & 63) == 0) { ws1[t >> 6] = s1; ws2[t >> 6] = s2; }
    __syncthreads();
    s1 = ws1[0] + ws1[1] + ws1[2] + ws1[3];
    s2 = ws2[0] + ws2[1] + ws2[2] + ws2[3];
    const float mean = s1 * (1.f / 1024.f);
    const float var = s2 * (1.f / 1024.f) - mean * mean;
    const float rstd = rsqrtf(var + 1e-5f);
    float4 gg = reinterpret_cast<const float4*>(g)[t];
    float4 bb = reinterpret_cast<const float4*>(be)[t];
    float o0 = (v0 - mean) * rstd * gg.x + bb.x;
    float o1 = (v1 - mean) * rstd * gg.y + bb.y;
    float o2 = (v2 - mean) * rstd * gg.z + bb.z;
    float o3 = (v3 - mean) * rstd * gg.w + bb.w;
    if (y) {
        float4 out = { o0, o1, o2, o3 };
        reinterpret_cast<float4*>(y + (size_t)row * 1024)[t] = out;
    }
    ushort4 ob = { f2b(o0), f2b(o1), f2b(o2), f2b(o3) };
    reinterpret_cast<ushort4*>(yb + (size_t)row * 1024)[t] = ob;
}

// ---------------------------------------------------------------------------
extern "C" void kernel_launch(void* const* d_in, const int* in_sizes, int n_in,
                              void* d_out, int out_size, void* d_ws, size_t ws_size,
                              hipStream_t stream) {
    const float* x_in = (const float*)d_in[0];
    const float* Wqkv = (const float*)d_in[1];
    const float* bqkv = (const float*)d_in[2];
    const float* W1   = (const float*)d_in[3];
    const float* b1   = (const float*)d_in[4];
    const float* W2   = (const float*)d_in[5];
    const float* b2   = (const float*)d_in[6];
    const float* g1   = (const float*)d_in[7];
    const float* be1  = (const float*)d_in[8];
    const float* g2   = (const float*)d_in[9];
    const float* be2  = (const float*)d_in[10];

    const int Bv = 2, N = 2048, L = 4, Hh = 16;
    const int R = Bv * N;  // 4096 token rows

    char* p = (char*)d_ws;
    auto alloc = [&](size_t bytes) { char* r = p; p += (bytes + 255) & ~(size_t)255; return r; };
    bf16*  Wqkvt = (bf16*)alloc((size_t)L * 3072 * 1024 * 2);
    bf16*  W1t   = (bf16*)alloc((size_t)L * 4096 * 1024 * 2);
    bf16*  W2t   = (bf16*)alloc((size_t)L * 1024 * 4096 * 2);
    bf16*  xb    = (bf16*)alloc((size_t)R * 1024 * 2);
    bf16*  qkvb  = (bf16*)alloc((size_t)R * 3072 * 2);
    float* obuf  = (float*)alloc((size_t)R * 1024 * 4);   // region: attn bf16 out + part0
    float* hbuf  = (float*)alloc((size_t)R * 1024 * 4);   // region: vtg
    bf16*  hb    = (bf16*)alloc((size_t)R * 1024 * 2);
    bf16*  f1b   = (bf16*)alloc((size_t)R * 4096 * 2);
    bf16*  vtg   = (bf16*)hbuf;   // 8.4MB V^T
    bf16*  ob    = (bf16*)obuf;   // attn bf16 output
    bf16*  part0 = (bf16*)obuf;   // split-K partials 0,1 (dead after LN1)
    bf16*  part2 = (bf16*)qkvb;   // split-K partials 2,3 (dead after attn)

    transpose_cast<<<dim3(3072 / 64, 1024 / 32, L), 256, 0, stream>>>(Wqkv, Wqkvt, 1024, 3072);
    transpose_cast<<<dim3(4096 / 64, 1024 / 32, L), 256, 0, stream>>>(W1, W1t, 1024, 4096);
    transpose_cast<<<dim3(1024 / 64, 4096 / 32, L), 256, 0, stream>>>(W2, W2t, 4096, 1024);
    cast_bf16_k<<<(R * 1024 / 4 + 255) / 256, 256, 0, stream>>>(x_in, xb, R * 1024 / 4);

    for (int l = 0; l < L; ++l) {
        // qkv = x @ Wqkv + bqkv; Q/K -> qkvb, V -> transposed vtg (4-phase EPI4)
        gemm256p<4><<<(R / 256) * (3072 / 256), 512, 0, stream>>>(
            xb, Wqkvt + (size_t)l * 3072 * 1024, bqkv + l * 3072, qkvb, vtg,
            R, 3072, 1024, 3072 / 256, (R / 256) * (3072 / 256), 1024);
        // o = softmax(q k^T / 32) v -> bf16   (QBLK=128, 512 blocks)
        attn_fwd<<<(N / 128) * (Bv * Hh), 256, 0, stream>>>(qkvb, vtg, ob, N);
        // h = LN(o + x) -> hb bf16  (residual: fp32 x_in layer 0, else bf16 xb)
        ln_res<<<R, 256, 0, stream>>>(ob, l == 0 ? x_in : nullptr,
                                      l == 0 ? nullptr : xb,
                                      g1 + l * 1024, be1 + l * 1024, hb);
        // f1 = gelu(h @ W1 + b1) -> bf16  (4-phase pipelined + swizzle)
        gemm256p<1><<<(R / 256) * (4096 / 256), 512, 0, stream>>>(
            hb, W1t + (size_t)l * 4096 * 1024, b1 + l * 4096, f1b, nullptr,
            R, 4096, 1024, 4096 / 256, (R / 256) * (4096 / 256), 1024);
        // f2 partials: f1 @ W2 split-K=4 -> bf16 into part0 (s0,s1) / part2 (s2,s3)
        gemm256p<3><<<(R / 256) * (1024 / 256) * 4, 512, 0, stream>>>(
            f1b, W2t + (size_t)l * 1024 * 4096, nullptr, part0, part2,
            R, 1024, 1024, 1024 / 256, (R / 256) * (1024 / 256), 4096);
        // x = LN(gelu(sum partials + b2) + h) -> xb bf16 (+ fp32 d_out last layer)
        ln_res_red4<<<R, 256, 0, stream>>>(part0, part2, b2 + l * 1024, hb,
                                           g2 + l * 1024, be2 + l * 1024,
                                           l == L - 1 ? (float*)d_out : nullptr,
                                           xb, (size_t)R * 1024);
    }
}